// Round 1
// baseline (2910.575 us; speedup 1.0000x reference)
//
#include <hip/hip_runtime.h>
#include <hip/hip_bf16.h>

// GCN layer: h = BN(ReLU(segment_sum(norm * (nf@W))[col] + b))
// Restructured: agg[c] = sum_e norm_e * nf[row_e]  (aggregate in input space),
// then out = agg @ W + b (linear commutes with the linear aggregation).
// d_out doubles as the agg buffer (GEMM runs in place, block-local rows).
//
// ws layout (floats): [0, N)         = deg -> dinv (in place)
//                     [N, N+128)     = sum_j
//                     [N+128, N+256) = sumsq_j
//                     [N+256, N+384) = scale_j
//                     [N+384, N+512) = shift_j

__global__ void k_init(float* __restrict__ deg, float* __restrict__ sums, int N) {
    int i = blockIdx.x * 256 + threadIdx.x;
    if (i < N) deg[i] = 1.0f;                      // self-loop weight
    if (blockIdx.x == 0 && threadIdx.x < 256) sums[threadIdx.x] = 0.0f;
}

__global__ void k_deg(const int* __restrict__ col, const float* __restrict__ w,
                      float* __restrict__ deg, int E) {
    int e = blockIdx.x * 256 + threadIdx.x;
    if (e < E) atomicAdd(&deg[col[e]], w[e]);
}

__global__ void k_dinv(float* __restrict__ deg, int N) {
    int i = blockIdx.x * 256 + threadIdx.x;
    if (i < N) {
        float d = deg[i];
        deg[i] = d > 0.0f ? rsqrtf(d) : 0.0f;
    }
}

// agg[i][j] = nf[i][j] * dinv[i]^2   (self-loop contribution, non-atomic init)
__global__ void k_self(const float* __restrict__ nf, const float* __restrict__ dinv,
                       float* __restrict__ agg, int N) {
    size_t i = (size_t)blockIdx.x * 256 + threadIdx.x;   // over N*32 float4s
    if (i >= (size_t)N * 32) return;
    int node = (int)(i >> 5);
    float s = dinv[node];
    s = s * s;
    float4 v = ((const float4*)nf)[i];
    v.x *= s; v.y *= s; v.z *= s; v.w *= s;
    ((float4*)agg)[i] = v;
}

// one wave per edge: 64 lanes x float2 = 128 features
__global__ __launch_bounds__(256) void k_scatter(
        const int* __restrict__ row, const int* __restrict__ col,
        const float* __restrict__ w, const float* __restrict__ dinv,
        const float* __restrict__ nf, float* __restrict__ agg, int E) {
    int wid = (int)(((size_t)blockIdx.x * blockDim.x + threadIdx.x) >> 6);
    int lane = threadIdx.x & 63;
    if (wid >= E) return;
    int r = row[wid], c = col[wid];
    float nrm = dinv[r] * w[wid] * dinv[c];
    float2 v = ((const float2*)(nf + (size_t)r * 128))[lane];
    float* dst = agg + (size_t)c * 128 + lane * 2;
    atomicAdd(dst,     v.x * nrm);
    atomicAdd(dst + 1, v.y * nrm);
}

// in-place: h[r0..r0+32) = relu(h_rows @ W + b). Rows staged to LDS first.
__global__ __launch_bounds__(256) void k_gemm(float* __restrict__ h,
        const float* __restrict__ W, const float* __restrict__ bias, int N) {
    __shared__ float Wl[128 * 128];   // 64 KB
    __shared__ float Rl[32 * 128];    // 16 KB
    int tid = threadIdx.x;
    int r0 = blockIdx.x * 32;
    const float4* Wv = (const float4*)W;
    float4* Wlv = (float4*)Wl;
#pragma unroll
    for (int i = 0; i < 16; ++i) Wlv[tid + 256 * i] = Wv[tid + 256 * i];
    const float4* Av = (const float4*)(h + (size_t)r0 * 128);
    float4* Rlv = (float4*)Rl;
#pragma unroll
    for (int i = 0; i < 4; ++i) Rlv[tid + 256 * i] = Av[tid + 256 * i];
    __syncthreads();

    int jq = tid & 31;       // col quad: cols 4*jq .. 4*jq+3
    int rg = tid >> 5;       // row group: rows rg*4 .. rg*4+3
    float acc[4][4] = {};
    for (int k = 0; k < 128; k += 4) {
        float4 a0 = *(float4*)&Rl[(rg * 4 + 0) * 128 + k];
        float4 a1 = *(float4*)&Rl[(rg * 4 + 1) * 128 + k];
        float4 a2 = *(float4*)&Rl[(rg * 4 + 2) * 128 + k];
        float4 a3 = *(float4*)&Rl[(rg * 4 + 3) * 128 + k];
#pragma unroll
        for (int kk = 0; kk < 4; ++kk) {
            float4 wv = *(float4*)&Wl[(k + kk) * 128 + jq * 4];
            float b0 = (&a0.x)[kk], b1 = (&a1.x)[kk], b2 = (&a2.x)[kk], b3 = (&a3.x)[kk];
            acc[0][0] += b0 * wv.x; acc[0][1] += b0 * wv.y; acc[0][2] += b0 * wv.z; acc[0][3] += b0 * wv.w;
            acc[1][0] += b1 * wv.x; acc[1][1] += b1 * wv.y; acc[1][2] += b1 * wv.z; acc[1][3] += b1 * wv.w;
            acc[2][0] += b2 * wv.x; acc[2][1] += b2 * wv.y; acc[2][2] += b2 * wv.z; acc[2][3] += b2 * wv.w;
            acc[3][0] += b3 * wv.x; acc[3][1] += b3 * wv.y; acc[3][2] += b3 * wv.z; acc[3][3] += b3 * wv.w;
        }
    }
    float4 bv = *(const float4*)&bias[jq * 4];
#pragma unroll
    for (int rr = 0; rr < 4; ++rr) {
        int r = r0 + rg * 4 + rr;
        if (r < N) {
            float4 o;
            o.x = fmaxf(acc[rr][0] + bv.x, 0.0f);
            o.y = fmaxf(acc[rr][1] + bv.y, 0.0f);
            o.z = fmaxf(acc[rr][2] + bv.z, 0.0f);
            o.w = fmaxf(acc[rr][3] + bv.w, 0.0f);
            *(float4*)&h[(size_t)r * 128 + jq * 4] = o;
        }
    }
}

__global__ __launch_bounds__(256) void k_bnstats(const float* __restrict__ h,
                                                 float* __restrict__ sums, int N) {
    int j = threadIdx.x & 127;
    int rg = threadIdx.x >> 7;   // 0..1
    float s = 0.0f, sq = 0.0f;
    for (int r = blockIdx.x * 2 + rg; r < N; r += gridDim.x * 2) {
        float v = h[(size_t)r * 128 + j];
        s += v;
        sq += v * v;
    }
    __shared__ float ls[512];
    ls[threadIdx.x] = s;
    ls[256 + threadIdx.x] = sq;
    __syncthreads();
    if (rg == 0) {
        atomicAdd(&sums[j],       s  + ls[threadIdx.x + 128]);
        atomicAdd(&sums[128 + j], sq + ls[256 + threadIdx.x + 128]);
    }
}

__global__ void k_bnfin(float* __restrict__ sums, const float* __restrict__ gamma,
                        const float* __restrict__ beta, int N) {
    int j = threadIdx.x;   // 128 threads
    float inv_n = 1.0f / (float)N;
    float mean = sums[j] * inv_n;
    float var = sums[128 + j] * inv_n - mean * mean;
    float sc = rsqrtf(var + 1e-5f) * gamma[j];
    sums[256 + j] = sc;
    sums[384 + j] = beta[j] - mean * sc;
}

__global__ void k_bnapply(float* __restrict__ h, const float* __restrict__ sums, size_t n4) {
    size_t i = (size_t)blockIdx.x * 256 + threadIdx.x;
    if (i >= n4) return;
    int j4 = (int)(i & 31);
    float4 v = ((float4*)h)[i];
    float4 sc = ((const float4*)(sums + 256))[j4];
    float4 sh = ((const float4*)(sums + 384))[j4];
    v.x = v.x * sc.x + sh.x;
    v.y = v.y * sc.y + sh.y;
    v.z = v.z * sc.z + sh.z;
    v.w = v.w * sc.w + sh.w;
    ((float4*)h)[i] = v;
}

extern "C" void kernel_launch(void* const* d_in, const int* in_sizes, int n_in,
                              void* d_out, int out_size, void* d_ws, size_t ws_size,
                              hipStream_t stream) {
    const float* nf    = (const float*)d_in[0];   // [N,128]
    const int*   ei    = (const int*)d_in[1];     // [2,E]
    const float* ew    = (const float*)d_in[2];   // [E]
    const float* W     = (const float*)d_in[3];   // [128,128]
    const float* bias  = (const float*)d_in[4];   // [128]
    const float* gamma = (const float*)d_in[5];   // [128]
    const float* beta  = (const float*)d_in[6];   // [128]
    float* out = (float*)d_out;

    const int N = in_sizes[0] / 128;
    const int E = in_sizes[2];
    const int* row = ei;        // sources
    const int* col = ei + E;    // targets (aggregation dim)

    float* deg  = (float*)d_ws;         // N floats; becomes dinv in place
    float* sums = (float*)d_ws + N;     // 512 floats: sum, sumsq, scale, shift

    int nb_n  = (N + 255) / 256;
    int nb_e  = (E + 255) / 256;
    int nb_v4 = (int)(((size_t)N * 32 + 255) / 256);

    k_init<<<nb_n, 256, 0, stream>>>(deg, sums, N);
    k_deg<<<nb_e, 256, 0, stream>>>(col, ew, deg, E);
    k_dinv<<<nb_n, 256, 0, stream>>>(deg, N);
    k_self<<<nb_v4, 256, 0, stream>>>(nf, deg, out, N);
    k_scatter<<<(E + 3) / 4, 256, 0, stream>>>(row, col, ew, deg, nf, out, E);
    k_gemm<<<(N + 31) / 32, 256, 0, stream>>>(out, W, bias, N);
    k_bnstats<<<256, 256, 0, stream>>>(out, sums, N);
    k_bnfin<<<1, 128, 0, stream>>>(sums, gamma, beta, N);
    k_bnapply<<<nb_v4, 256, 0, stream>>>(out, sums, (size_t)N * 32);
}

// Round 2
// 1016.074 us; speedup vs baseline: 2.8645x; 2.8645x over previous
//
#include <hip/hip_runtime.h>
#include <hip/hip_bf16.h>

// GCN layer: h = BN(ReLU(segment_sum(norm * (nf@W))[col] + b))
// Aggregate raw features first (agg[c] = sum norm*nf[row]), then GEMM.
// Round 1: atomic scatter (409.6M atomics, 3.28 GB writes) -> CSR gather
// (one 512B store per node, nf gathers served by L2/L3).
//
// ws layout (4B words):
//   [0, N)             dinv
//   [N, 2N+1)          ptr (CSR offsets, N+1 ints)
//   [2N+1, 3N+1)       cnt  (counts -> cursor, in place)
//   [3N+1, 3N+513)     sums (BN: sum, sumsq, scale, shift)
//   [pad to even]
//   [...]              packed (E x int2: row, weight-bits)

__global__ void k_init(int* __restrict__ cnt, float* __restrict__ sums, int N) {
    int i = blockIdx.x * 256 + threadIdx.x;
    if (i < N) cnt[i] = 0;
    if (blockIdx.x == 0 && threadIdx.x < 512) sums[threadIdx.x] = 0.0f;
}

__global__ void k_count(const int* __restrict__ col, int* __restrict__ cnt, int E) {
    int e = blockIdx.x * 256 + threadIdx.x;
    if (e < E) atomicAdd(&cnt[col[e]], 1);
}

// single-block exclusive scan: counts -> ptr[0..N], and cnt becomes cursor
__global__ __launch_bounds__(1024) void k_scan(int* __restrict__ cnt,
                                               int* __restrict__ ptr, int N) {
    __shared__ int ls[1024];
    int t = threadIdx.x;
    int chunk = (N + 1023) / 1024;
    int b = t * chunk, e = min(b + chunk, N);
    int s = 0;
    for (int i = b; i < e; ++i) s += cnt[i];
    ls[t] = s;
    __syncthreads();
    for (int off = 1; off < 1024; off <<= 1) {
        int v = (t >= off) ? ls[t - off] : 0;
        __syncthreads();
        ls[t] += v;
        __syncthreads();
    }
    int run = ls[t] - s;   // exclusive prefix of this thread's chunk
    for (int i = b; i < e; ++i) {
        int c = cnt[i];
        ptr[i] = run;
        cnt[i] = run;      // cursor
        run += c;
    }
    if (t == 1023) ptr[N] = ls[1023];
}

__global__ void k_fill(const int* __restrict__ row, const int* __restrict__ col,
                       const float* __restrict__ w, int* __restrict__ cursor,
                       int2* __restrict__ packed, int E) {
    int e = blockIdx.x * 256 + threadIdx.x;
    if (e < E) {
        int pos = atomicAdd(&cursor[col[e]], 1);
        packed[pos] = make_int2(row[e], __float_as_int(w[e]));
    }
}

// wave per node: deg = 1 + sum w  -> dinv
__global__ __launch_bounds__(256) void k_degw(const int2* __restrict__ packed,
                                              const int* __restrict__ ptr,
                                              float* __restrict__ dinv, int N) {
    int wid = (int)(((size_t)blockIdx.x * 256 + threadIdx.x) >> 6);
    int lane = threadIdx.x & 63;
    if (wid >= N) return;
    int beg = ptr[wid], end = ptr[wid + 1];
    float s = 0.0f;
    for (int k = beg + lane; k < end; k += 64) s += __int_as_float(packed[k].y);
#pragma unroll
    for (int off = 32; off; off >>= 1) s += __shfl_xor(s, off);
    if (lane == 0) {
        float d = 1.0f + s;
        dinv[wid] = d > 0.0f ? rsqrtf(d) : 0.0f;
    }
}

// wave per node; two 32-lane halves each take one edge (float4/lane)
__global__ __launch_bounds__(256) void k_gather(
        const int2* __restrict__ packed, const int* __restrict__ ptr,
        const float* __restrict__ dinv, const float* __restrict__ nf,
        float* __restrict__ out, int N) {
    int wid = (int)(((size_t)blockIdx.x * 256 + threadIdx.x) >> 6);
    int lane = threadIdx.x & 63;
    if (wid >= N) return;
    int c = wid;
    int beg = ptr[c], end = ptr[c + 1];
    float dc = dinv[c];
    int half = lane >> 5;
    int fl = lane & 31;          // float4 slot: features [4*fl, 4*fl+4)
    float4 acc = {0.f, 0.f, 0.f, 0.f};
    for (int k = beg; k < end; k += 2) {
        int idx = k + half;
        bool v = idx < end;
        int2 p = packed[v ? idx : end - 1];
        float nrm = v ? dc * __int_as_float(p.y) * dinv[p.x] : 0.0f;
        float4 x = ((const float4*)(nf + (size_t)p.x * 128))[fl];
        acc.x += nrm * x.x; acc.y += nrm * x.y;
        acc.z += nrm * x.z; acc.w += nrm * x.w;
    }
    acc.x += __shfl_xor(acc.x, 32);
    acc.y += __shfl_xor(acc.y, 32);
    acc.z += __shfl_xor(acc.z, 32);
    acc.w += __shfl_xor(acc.w, 32);
    if (half == 0) {
        float s2 = dc * dc;
        float4 sf = ((const float4*)(nf + (size_t)c * 128))[fl];
        acc.x += s2 * sf.x; acc.y += s2 * sf.y;
        acc.z += s2 * sf.z; acc.w += s2 * sf.w;
        ((float4*)(out + (size_t)c * 128))[fl] = acc;
    }
}

// ---------- fallback path (ws too small): original atomic scatter ----------
__global__ void k_initA(float* __restrict__ deg, float* __restrict__ sums, int N) {
    int i = blockIdx.x * 256 + threadIdx.x;
    if (i < N) deg[i] = 1.0f;
    if (blockIdx.x == 0 && threadIdx.x < 512) sums[threadIdx.x] = 0.0f;
}
__global__ void k_deg(const int* __restrict__ col, const float* __restrict__ w,
                      float* __restrict__ deg, int E) {
    int e = blockIdx.x * 256 + threadIdx.x;
    if (e < E) atomicAdd(&deg[col[e]], w[e]);
}
__global__ void k_dinv(float* __restrict__ deg, int N) {
    int i = blockIdx.x * 256 + threadIdx.x;
    if (i < N) { float d = deg[i]; deg[i] = d > 0.0f ? rsqrtf(d) : 0.0f; }
}
__global__ void k_self(const float* __restrict__ nf, const float* __restrict__ dinv,
                       float* __restrict__ agg, int N) {
    size_t i = (size_t)blockIdx.x * 256 + threadIdx.x;
    if (i >= (size_t)N * 32) return;
    int node = (int)(i >> 5);
    float s = dinv[node]; s = s * s;
    float4 v = ((const float4*)nf)[i];
    v.x *= s; v.y *= s; v.z *= s; v.w *= s;
    ((float4*)agg)[i] = v;
}
__global__ __launch_bounds__(256) void k_scatter(
        const int* __restrict__ row, const int* __restrict__ col,
        const float* __restrict__ w, const float* __restrict__ dinv,
        const float* __restrict__ nf, float* __restrict__ agg, int E) {
    int wid = (int)(((size_t)blockIdx.x * blockDim.x + threadIdx.x) >> 6);
    int lane = threadIdx.x & 63;
    if (wid >= E) return;
    int r = row[wid], c = col[wid];
    float nrm = dinv[r] * w[wid] * dinv[c];
    float2 v = ((const float2*)(nf + (size_t)r * 128))[lane];
    float* dst = agg + (size_t)c * 128 + lane * 2;
    atomicAdd(dst, v.x * nrm);
    atomicAdd(dst + 1, v.y * nrm);
}
// ---------------------------------------------------------------------------

// in-place: h[r0..r0+32) = relu(h_rows @ W + b)
__global__ __launch_bounds__(256) void k_gemm(float* __restrict__ h,
        const float* __restrict__ W, const float* __restrict__ bias, int N) {
    __shared__ float Wl[128 * 128];
    __shared__ float Rl[32 * 128];
    int tid = threadIdx.x;
    int r0 = blockIdx.x * 32;
    const float4* Wv = (const float4*)W;
    float4* Wlv = (float4*)Wl;
#pragma unroll
    for (int i = 0; i < 16; ++i) Wlv[tid + 256 * i] = Wv[tid + 256 * i];
    const float4* Av = (const float4*)(h + (size_t)r0 * 128);
    float4* Rlv = (float4*)Rl;
#pragma unroll
    for (int i = 0; i < 4; ++i) Rlv[tid + 256 * i] = Av[tid + 256 * i];
    __syncthreads();

    int jq = tid & 31;
    int rg = tid >> 5;
    float acc[4][4] = {};
    for (int k = 0; k < 128; k += 4) {
        float4 a0 = *(float4*)&Rl[(rg * 4 + 0) * 128 + k];
        float4 a1 = *(float4*)&Rl[(rg * 4 + 1) * 128 + k];
        float4 a2 = *(float4*)&Rl[(rg * 4 + 2) * 128 + k];
        float4 a3 = *(float4*)&Rl[(rg * 4 + 3) * 128 + k];
#pragma unroll
        for (int kk = 0; kk < 4; ++kk) {
            float4 wv = *(float4*)&Wl[(k + kk) * 128 + jq * 4];
            float b0 = (&a0.x)[kk], b1 = (&a1.x)[kk], b2 = (&a2.x)[kk], b3 = (&a3.x)[kk];
            acc[0][0] += b0 * wv.x; acc[0][1] += b0 * wv.y; acc[0][2] += b0 * wv.z; acc[0][3] += b0 * wv.w;
            acc[1][0] += b1 * wv.x; acc[1][1] += b1 * wv.y; acc[1][2] += b1 * wv.z; acc[1][3] += b1 * wv.w;
            acc[2][0] += b2 * wv.x; acc[2][1] += b2 * wv.y; acc[2][2] += b2 * wv.z; acc[2][3] += b2 * wv.w;
            acc[3][0] += b3 * wv.x; acc[3][1] += b3 * wv.y; acc[3][2] += b3 * wv.z; acc[3][3] += b3 * wv.w;
        }
    }
    float4 bv = *(const float4*)&bias[jq * 4];
#pragma unroll
    for (int rr = 0; rr < 4; ++rr) {
        int r = r0 + rg * 4 + rr;
        if (r < N) {
            float4 o;
            o.x = fmaxf(acc[rr][0] + bv.x, 0.0f);
            o.y = fmaxf(acc[rr][1] + bv.y, 0.0f);
            o.z = fmaxf(acc[rr][2] + bv.z, 0.0f);
            o.w = fmaxf(acc[rr][3] + bv.w, 0.0f);
            *(float4*)&h[(size_t)r * 128 + jq * 4] = o;
        }
    }
}

__global__ __launch_bounds__(256) void k_bnstats(const float* __restrict__ h,
                                                 float* __restrict__ sums, int N) {
    int j = threadIdx.x & 127;
    int rg = threadIdx.x >> 7;
    float s = 0.0f, sq = 0.0f;
    for (int r = blockIdx.x * 2 + rg; r < N; r += gridDim.x * 2) {
        float v = h[(size_t)r * 128 + j];
        s += v; sq += v * v;
    }
    __shared__ float ls[512];
    ls[threadIdx.x] = s;
    ls[256 + threadIdx.x] = sq;
    __syncthreads();
    if (rg == 0) {
        atomicAdd(&sums[j],       s  + ls[threadIdx.x + 128]);
        atomicAdd(&sums[128 + j], sq + ls[256 + threadIdx.x + 128]);
    }
}

__global__ void k_bnfin(float* __restrict__ sums, const float* __restrict__ gamma,
                        const float* __restrict__ beta, int N) {
    int j = threadIdx.x;
    float inv_n = 1.0f / (float)N;
    float mean = sums[j] * inv_n;
    float var = sums[128 + j] * inv_n - mean * mean;
    float sc = rsqrtf(var + 1e-5f) * gamma[j];
    sums[256 + j] = sc;
    sums[384 + j] = beta[j] - mean * sc;
}

__global__ void k_bnapply(float* __restrict__ h, const float* __restrict__ sums, size_t n4) {
    size_t i = (size_t)blockIdx.x * 256 + threadIdx.x;
    if (i >= n4) return;
    int j4 = (int)(i & 31);
    float4 v = ((float4*)h)[i];
    float4 sc = ((const float4*)(sums + 256))[j4];
    float4 sh = ((const float4*)(sums + 384))[j4];
    v.x = v.x * sc.x + sh.x;
    v.y = v.y * sc.y + sh.y;
    v.z = v.z * sc.z + sh.z;
    v.w = v.w * sc.w + sh.w;
    ((float4*)h)[i] = v;
}

extern "C" void kernel_launch(void* const* d_in, const int* in_sizes, int n_in,
                              void* d_out, int out_size, void* d_ws, size_t ws_size,
                              hipStream_t stream) {
    const float* nf    = (const float*)d_in[0];
    const int*   ei    = (const int*)d_in[1];
    const float* ew    = (const float*)d_in[2];
    const float* W     = (const float*)d_in[3];
    const float* bias  = (const float*)d_in[4];
    const float* gamma = (const float*)d_in[5];
    const float* beta  = (const float*)d_in[6];
    float* out = (float*)d_out;

    const int N = in_sizes[0] / 128;
    const int E = in_sizes[2];
    const int* row = ei;
    const int* col = ei + E;

    int nb_n  = (N + 255) / 256;
    int nb_e  = (E + 255) / 256;
    int nb_w  = (int)(((size_t)N * 64 + 255) / 256);   // wave per node
    int nb_v4 = (int)(((size_t)N * 32 + 255) / 256);

    // ws layout
    float* dinv   = (float*)d_ws;
    int*   ptr    = (int*)d_ws + N;
    int*   cnt    = (int*)d_ws + 2 * N + 1;
    float* sums   = (float*)d_ws + 3 * N + 1;
    size_t pk_off = (size_t)(3 * N + 513 + 1) & ~(size_t)1;
    int2*  packed = (int2*)((int*)d_ws + pk_off);
    size_t need   = (pk_off + (size_t)E * 2) * 4;

    if (ws_size >= need) {
        k_init<<<nb_n, 256, 0, stream>>>(cnt, sums, N);
        k_count<<<nb_e, 256, 0, stream>>>(col, cnt, E);
        k_scan<<<1, 1024, 0, stream>>>(cnt, ptr, N);
        k_fill<<<nb_e, 256, 0, stream>>>(row, col, ew, cnt, packed, E);
        k_degw<<<nb_w, 256, 0, stream>>>(packed, ptr, dinv, N);
        k_gather<<<nb_w, 256, 0, stream>>>(packed, ptr, dinv, nf, out, N);
    } else {
        float* deg = (float*)d_ws;
        float* sm  = (float*)d_ws + N;
        k_initA<<<nb_n, 256, 0, stream>>>(deg, sm, N);
        k_deg<<<nb_e, 256, 0, stream>>>(col, ew, deg, E);
        k_dinv<<<nb_n, 256, 0, stream>>>(deg, N);
        k_self<<<nb_v4, 256, 0, stream>>>(nf, deg, out, N);
        k_scatter<<<(E + 3) / 4, 256, 0, stream>>>(row, col, ew, deg, nf, out, E);
        sums = sm;
    }
    k_gemm<<<(N + 31) / 32, 256, 0, stream>>>(out, W, bias, N);
    k_bnstats<<<256, 256, 0, stream>>>(out, sums, N);
    k_bnfin<<<1, 128, 0, stream>>>(sums, gamma, beta, N);
    k_bnapply<<<nb_v4, 256, 0, stream>>>(out, sums, (size_t)N * 32);
}

// Round 3
// 701.107 us; speedup vs baseline: 4.1514x; 1.4492x over previous
//
#include <hip/hip_runtime.h>
#include <hip/hip_bf16.h>

// GCN layer: h = BN(ReLU(segment_sum(norm * (nf@W))[col] + b))
// Aggregate raw features first (agg[c] = sum norm*nf[row]), then GEMM.
// R1: atomic scatter -> CSR gather.
// R2: bf16 feature table (halve gather bytes), 4-edges-in-flight gather,
//     tiled dbuf GEMM with fused BN stats, hierarchical scan.
//
// ws layout (4B words):
//   [0, N)               dinv
//   [N, 2N+1)            ptr (CSR offsets)
//   [2N+1, 3N+1)         cnt (counts -> cursor)
//   [3N+1, 3N+513)       sums (BN: sum, sumsq, scale, shift)
//   [3N+513, 3N+1025)    bsum (scan partials)
//   [align4]             packed (E x int2: row, w-bits)
//   [align4]             tab (N x 128 bf16 = N*64 words)

__device__ __forceinline__ unsigned bf16rn(float f) {
    unsigned x = __float_as_uint(f);
    return (x + 0x7fffu + ((x >> 16) & 1u)) >> 16;
}
__device__ __forceinline__ float bflo(unsigned u) { return __uint_as_float(u << 16); }
__device__ __forceinline__ float bfhi(unsigned u) { return __uint_as_float(u & 0xffff0000u); }

__global__ void k_init(int* __restrict__ cnt, float* __restrict__ sums, int N) {
    int i = blockIdx.x * 256 + threadIdx.x;
    if (i < N) cnt[i] = 0;
    if (blockIdx.x == 0 && threadIdx.x < 512) sums[threadIdx.x] = 0.0f;
}

__global__ void k_conv(const float* __restrict__ nf, uint4* __restrict__ tab, size_t n8) {
    size_t i = (size_t)blockIdx.x * 256 + threadIdx.x;
    if (i >= n8) return;
    const float4* src = (const float4*)nf;
    float4 a = src[2 * i], b = src[2 * i + 1];
    uint4 r;
    r.x = bf16rn(a.x) | (bf16rn(a.y) << 16);
    r.y = bf16rn(a.z) | (bf16rn(a.w) << 16);
    r.z = bf16rn(b.x) | (bf16rn(b.y) << 16);
    r.w = bf16rn(b.z) | (bf16rn(b.w) << 16);
    tab[i] = r;
}

__global__ void k_count(const int* __restrict__ col, int* __restrict__ cnt, int E) {
    int e = blockIdx.x * 256 + threadIdx.x;
    if (e < E) atomicAdd(&cnt[col[e]], 1);
}

// hierarchical exclusive scan: kS1 (per-block) -> kS2 (block sums) -> kS3 (apply)
__global__ __launch_bounds__(256) void kS1(const int* __restrict__ cnt,
                                           int* __restrict__ ptr,
                                           int* __restrict__ bsum, int N) {
    __shared__ int ls[256];
    int t = threadIdx.x, i = blockIdx.x * 256 + t;
    int v = (i < N) ? cnt[i] : 0;
    ls[t] = v;
    __syncthreads();
    for (int off = 1; off < 256; off <<= 1) {
        int u = (t >= off) ? ls[t - off] : 0;
        __syncthreads();
        ls[t] += u;
        __syncthreads();
    }
    if (i < N) ptr[i] = ls[t] - v;
    if (t == 255) bsum[blockIdx.x] = ls[255];
}

__global__ __launch_bounds__(512) void kS2(int* __restrict__ bsum,
                                           int* __restrict__ ptr, int NB, int N) {
    __shared__ int ls[512];
    int t = threadIdx.x;
    int chunk = (NB + 511) / 512;
    int b = t * chunk, e = min(b + chunk, NB);
    int s = 0;
    for (int i = b; i < e; ++i) s += bsum[i];
    ls[t] = s;
    __syncthreads();
    for (int off = 1; off < 512; off <<= 1) {
        int u = (t >= off) ? ls[t - off] : 0;
        __syncthreads();
        ls[t] += u;
        __syncthreads();
    }
    int run = ls[t] - s;
    for (int i = b; i < e; ++i) { int c = bsum[i]; bsum[i] = run; run += c; }
    if (t == 511) ptr[N] = ls[511];
}

__global__ void kS3(int* __restrict__ ptr, int* __restrict__ cnt,
                    const int* __restrict__ bsum, int N) {
    int i = blockIdx.x * 256 + threadIdx.x;
    if (i >= N) return;
    int p = ptr[i] + bsum[blockIdx.x];
    ptr[i] = p;
    cnt[i] = p;
}

__global__ void k_fill(const int* __restrict__ row, const int* __restrict__ col,
                       const float* __restrict__ w, int* __restrict__ cursor,
                       int2* __restrict__ packed, int E) {
    int e = blockIdx.x * 256 + threadIdx.x;
    if (e < E) {
        int pos = atomicAdd(&cursor[col[e]], 1);
        packed[pos] = make_int2(row[e], __float_as_int(w[e]));
    }
}

// wave per node: deg = 1 + sum w -> dinv
__global__ __launch_bounds__(256) void k_degw(const int2* __restrict__ packed,
                                              const int* __restrict__ ptr,
                                              float* __restrict__ dinv, int N) {
    int wid = (int)(((size_t)blockIdx.x * 256 + threadIdx.x) >> 6);
    int lane = threadIdx.x & 63;
    if (wid >= N) return;
    int beg = ptr[wid], end = ptr[wid + 1];
    float s = 0.0f;
    for (int k = beg + lane; k < end; k += 64) s += __int_as_float(packed[k].y);
#pragma unroll
    for (int off = 32; off; off >>= 1) s += __shfl_xor(s, off);
    if (lane == 0) {
        float d = 1.0f + s;
        dinv[wid] = d > 0.0f ? rsqrtf(d) : 0.0f;
    }
}

// bf16-table gather: wave per node, 4 quarters x 1 edge, 16B loads/lane
__global__ __launch_bounds__(256) void k_gatherb(
        const int2* __restrict__ packed, const int* __restrict__ ptr,
        const float* __restrict__ dinv, const unsigned* __restrict__ tab,
        float* __restrict__ out, int N) {
    int wid = (int)(((size_t)blockIdx.x * 256 + threadIdx.x) >> 6);
    int lane = threadIdx.x & 63;
    if (wid >= N) return;
    int c = wid;
    int beg = ptr[c], end = ptr[c + 1];
    float dc = dinv[c];
    int q = lane >> 4;       // edge slot
    int fl = lane & 15;      // features [8*fl, 8*fl+8)
    float acc[8] = {};
    for (int k = beg; k < end; k += 4) {
        int idx = k + q;
        bool valid = idx < end;
        int2 p = packed[valid ? idx : beg];
        float nrm = valid ? dc * __int_as_float(p.y) * dinv[p.x] : 0.0f;
        uint4 t = *(const uint4*)(tab + (size_t)p.x * 64 + fl * 4);
        acc[0] += nrm * bflo(t.x); acc[1] += nrm * bfhi(t.x);
        acc[2] += nrm * bflo(t.y); acc[3] += nrm * bfhi(t.y);
        acc[4] += nrm * bflo(t.z); acc[5] += nrm * bfhi(t.z);
        acc[6] += nrm * bflo(t.w); acc[7] += nrm * bfhi(t.w);
    }
#pragma unroll
    for (int j = 0; j < 8; ++j) {
        acc[j] += __shfl_xor(acc[j], 16);
        acc[j] += __shfl_xor(acc[j], 32);
    }
    if (q == 0) {
        uint4 t = *(const uint4*)(tab + (size_t)c * 64 + fl * 4);
        float s2 = dc * dc;
        acc[0] += s2 * bflo(t.x); acc[1] += s2 * bfhi(t.x);
        acc[2] += s2 * bflo(t.y); acc[3] += s2 * bfhi(t.y);
        acc[4] += s2 * bflo(t.z); acc[5] += s2 * bfhi(t.z);
        acc[6] += s2 * bflo(t.w); acc[7] += s2 * bfhi(t.w);
        float4* dst = (float4*)(out + (size_t)c * 128 + fl * 8);
        dst[0] = make_float4(acc[0], acc[1], acc[2], acc[3]);
        dst[1] = make_float4(acc[4], acc[5], acc[6], acc[7]);
    }
}

// f32 gather fallback (ws too small for bf16 table)
__global__ __launch_bounds__(256) void k_gather(
        const int2* __restrict__ packed, const int* __restrict__ ptr,
        const float* __restrict__ dinv, const float* __restrict__ nf,
        float* __restrict__ out, int N) {
    int wid = (int)(((size_t)blockIdx.x * 256 + threadIdx.x) >> 6);
    int lane = threadIdx.x & 63;
    if (wid >= N) return;
    int c = wid;
    int beg = ptr[c], end = ptr[c + 1];
    float dc = dinv[c];
    int half = lane >> 5;
    int fl = lane & 31;
    float4 acc = {0.f, 0.f, 0.f, 0.f};
    for (int k = beg; k < end; k += 2) {
        int idx = k + half;
        bool v = idx < end;
        int2 p = packed[v ? idx : beg];
        float nrm = v ? dc * __int_as_float(p.y) * dinv[p.x] : 0.0f;
        float4 x = ((const float4*)(nf + (size_t)p.x * 128))[fl];
        acc.x += nrm * x.x; acc.y += nrm * x.y;
        acc.z += nrm * x.z; acc.w += nrm * x.w;
    }
    acc.x += __shfl_xor(acc.x, 32);
    acc.y += __shfl_xor(acc.y, 32);
    acc.z += __shfl_xor(acc.z, 32);
    acc.w += __shfl_xor(acc.w, 32);
    if (half == 0) {
        float s2 = dc * dc;
        float4 sf = ((const float4*)(nf + (size_t)c * 128))[fl];
        acc.x += s2 * sf.x; acc.y += s2 * sf.y;
        acc.z += s2 * sf.z; acc.w += s2 * sf.w;
        ((float4*)(out + (size_t)c * 128))[fl] = acc;
    }
}

// ---------- atomic-scatter full fallback ----------
__global__ void k_initA(float* __restrict__ deg, float* __restrict__ sums, int N) {
    int i = blockIdx.x * 256 + threadIdx.x;
    if (i < N) deg[i] = 1.0f;
    if (blockIdx.x == 0 && threadIdx.x < 512) sums[threadIdx.x] = 0.0f;
}
__global__ void k_deg(const int* __restrict__ col, const float* __restrict__ w,
                      float* __restrict__ deg, int E) {
    int e = blockIdx.x * 256 + threadIdx.x;
    if (e < E) atomicAdd(&deg[col[e]], w[e]);
}
__global__ void k_dinv(float* __restrict__ deg, int N) {
    int i = blockIdx.x * 256 + threadIdx.x;
    if (i < N) { float d = deg[i]; deg[i] = d > 0.0f ? rsqrtf(d) : 0.0f; }
}
__global__ void k_self(const float* __restrict__ nf, const float* __restrict__ dinv,
                       float* __restrict__ agg, int N) {
    size_t i = (size_t)blockIdx.x * 256 + threadIdx.x;
    if (i >= (size_t)N * 32) return;
    int node = (int)(i >> 5);
    float s = dinv[node]; s = s * s;
    float4 v = ((const float4*)nf)[i];
    v.x *= s; v.y *= s; v.z *= s; v.w *= s;
    ((float4*)agg)[i] = v;
}
__global__ __launch_bounds__(256) void k_scatter(
        const int* __restrict__ row, const int* __restrict__ col,
        const float* __restrict__ w, const float* __restrict__ dinv,
        const float* __restrict__ nf, float* __restrict__ agg, int E) {
    int wid = (int)(((size_t)blockIdx.x * blockDim.x + threadIdx.x) >> 6);
    int lane = threadIdx.x & 63;
    if (wid >= E) return;
    int r = row[wid], c = col[wid];
    float nrm = dinv[r] * w[wid] * dinv[c];
    float2 v = ((const float2*)(nf + (size_t)r * 128))[lane];
    float* dst = agg + (size_t)c * 128 + lane * 2;
    atomicAdd(dst, v.x * nrm);
    atomicAdd(dst + 1, v.y * nrm);
}
// ---------------------------------------------------

// in-place tiled GEMM: h[block rows] = relu(h @ W + b), fused BN partial sums.
// BM=128, BK=32, 256 threads, 8x8 acc/thread, double-buffered LDS.
__global__ __launch_bounds__(256) void k_gemm2(float* __restrict__ h,
        const float* __restrict__ W, const float* __restrict__ bias,
        float* __restrict__ sums, int N) {
    __shared__ float At[2][32][132];   // A transposed: [k][row]
    __shared__ float Wt[2][32][132];   // [k][col]
    int tid = threadIdx.x;
    int tx = tid & 15, ty = tid >> 4;
    int r0 = blockIdx.x * 128;

#define STAGE_A(buf, k0)                                                     \
    _Pragma("unroll")                                                        \
    for (int i = 0; i < 4; ++i) {                                            \
        int idx = tid + 256 * i;                                             \
        int row = idx >> 3, c4 = idx & 7;                                    \
        int gr = r0 + row; if (gr > N - 1) gr = N - 1;                       \
        float4 v = *(const float4*)&h[(size_t)gr * 128 + (k0) + c4 * 4];     \
        At[buf][c4 * 4 + 0][row] = v.x;                                      \
        At[buf][c4 * 4 + 1][row] = v.y;                                      \
        At[buf][c4 * 4 + 2][row] = v.z;                                      \
        At[buf][c4 * 4 + 3][row] = v.w;                                      \
    }
#define STAGE_W(buf, k0)                                                     \
    _Pragma("unroll")                                                        \
    for (int i = 0; i < 4; ++i) {                                            \
        int idx = tid + 256 * i;                                             \
        int kk = idx >> 5, c4 = idx & 31;                                    \
        float4 v = *(const float4*)&W[(size_t)((k0) + kk) * 128 + c4 * 4];   \
        *(float4*)&Wt[buf][kk][c4 * 4] = v;                                  \
    }

    STAGE_A(0, 0)
    STAGE_W(0, 0)
    float acc[8][8] = {};
    for (int t = 0; t < 4; ++t) {
        __syncthreads();
        if (t < 3) {
            int nb = (t + 1) & 1;
            STAGE_A(nb, (t + 1) * 32)
            STAGE_W(nb, (t + 1) * 32)
        }
        int kb = t & 1;
#pragma unroll
        for (int k = 0; k < 32; ++k) {
            float a[8], w[8];
            *(float4*)&a[0] = *(float4*)&At[kb][k][ty * 8];
            *(float4*)&a[4] = *(float4*)&At[kb][k][ty * 8 + 4];
            *(float4*)&w[0] = *(float4*)&Wt[kb][k][tx * 8];
            *(float4*)&w[4] = *(float4*)&Wt[kb][k][tx * 8 + 4];
#pragma unroll
            for (int r = 0; r < 8; ++r)
#pragma unroll
                for (int cc = 0; cc < 8; ++cc)
                    acc[r][cc] += a[r] * w[cc];
        }
    }

    float bv[8];
    *(float4*)&bv[0] = *(const float4*)&bias[tx * 8];
    *(float4*)&bv[4] = *(const float4*)&bias[tx * 8 + 4];
    float s[8] = {}, sq[8] = {};
#pragma unroll
    for (int r = 0; r < 8; ++r) {
        int gr = r0 + ty * 8 + r;
        if (gr < N) {
            float o[8];
#pragma unroll
            for (int cc = 0; cc < 8; ++cc) {
                o[cc] = fmaxf(acc[r][cc] + bv[cc], 0.0f);
                s[cc] += o[cc];
                sq[cc] += o[cc] * o[cc];
            }
            float4* dst = (float4*)&h[(size_t)gr * 128 + tx * 8];
            dst[0] = make_float4(o[0], o[1], o[2], o[3]);
            dst[1] = make_float4(o[4], o[5], o[6], o[7]);
        }
    }
    // BN partial reduce via LDS (reuse At region)
    float* ls = &At[0][0][0];   // need 2*2048 floats = 16 KB
    __syncthreads();
#pragma unroll
    for (int cc = 0; cc < 8; ++cc) {
        ls[ty * 128 + tx * 8 + cc] = s[cc];
        ls[2048 + ty * 128 + tx * 8 + cc] = sq[cc];
    }
    __syncthreads();
    if (tid < 128) {
        float ssum = 0.f, sqsum = 0.f;
#pragma unroll
        for (int u = 0; u < 16; ++u) {
            ssum += ls[u * 128 + tid];
            sqsum += ls[2048 + u * 128 + tid];
        }
        atomicAdd(&sums[tid], ssum);
        atomicAdd(&sums[128 + tid], sqsum);
    }
#undef STAGE_A
#undef STAGE_W
}

__global__ void k_bnfin(float* __restrict__ sums, const float* __restrict__ gamma,
                        const float* __restrict__ beta, int N) {
    int j = threadIdx.x;
    float inv_n = 1.0f / (float)N;
    float mean = sums[j] * inv_n;
    float var = sums[128 + j] * inv_n - mean * mean;
    float sc = rsqrtf(var + 1e-5f) * gamma[j];
    sums[256 + j] = sc;
    sums[384 + j] = beta[j] - mean * sc;
}

__global__ void k_bnapply(float* __restrict__ h, const float* __restrict__ sums, size_t n4) {
    size_t i = (size_t)blockIdx.x * 256 + threadIdx.x;
    if (i >= n4) return;
    int j4 = (int)(i & 31);
    float4 v = ((float4*)h)[i];
    float4 sc = ((const float4*)(sums + 256))[j4];
    float4 sh = ((const float4*)(sums + 384))[j4];
    v.x = v.x * sc.x + sh.x;
    v.y = v.y * sc.y + sh.y;
    v.z = v.z * sc.z + sh.z;
    v.w = v.w * sc.w + sh.w;
    ((float4*)h)[i] = v;
}

extern "C" void kernel_launch(void* const* d_in, const int* in_sizes, int n_in,
                              void* d_out, int out_size, void* d_ws, size_t ws_size,
                              hipStream_t stream) {
    const float* nf    = (const float*)d_in[0];
    const int*   ei    = (const int*)d_in[1];
    const float* ew    = (const float*)d_in[2];
    const float* W     = (const float*)d_in[3];
    const float* bias  = (const float*)d_in[4];
    const float* gamma = (const float*)d_in[5];
    const float* beta  = (const float*)d_in[6];
    float* out = (float*)d_out;

    const int N = in_sizes[0] / 128;
    const int E = in_sizes[2];
    const int* row = ei;
    const int* col = ei + E;

    int nb_n  = (N + 255) / 256;
    int nb_e  = (E + 255) / 256;
    int nb_w  = (int)(((size_t)N + 3) / 4);          // wave per node, 4 waves/block
    int nb_v4 = (int)(((size_t)N * 32 + 255) / 256);

    // ws layout
    float* dinv = (float*)d_ws;
    int*   ptr  = (int*)d_ws + N;
    int*   cnt  = (int*)d_ws + 2 * N + 1;
    float* sums = (float*)d_ws + 3 * N + 1;
    int*   bsum = (int*)d_ws + 3 * N + 513;
    size_t pk_off  = ((size_t)(3 * N + 1025) + 3) & ~(size_t)3;
    int2*  packed  = (int2*)((int*)d_ws + pk_off);
    size_t tab_off = (pk_off + (size_t)2 * E + 3) & ~(size_t)3;
    unsigned* tab  = (unsigned*)((int*)d_ws + tab_off);
    size_t need_csr  = (pk_off + (size_t)2 * E) * 4;
    size_t need_full = (tab_off + (size_t)64 * N) * 4;

    if (ws_size >= need_csr) {
        k_init<<<nb_n, 256, 0, stream>>>(cnt, sums, N);
        if (ws_size >= need_full) {
            size_t n8 = (size_t)N * 16;
            k_conv<<<(int)((n8 + 255) / 256), 256, 0, stream>>>(nf, (uint4*)tab, n8);
        }
        k_count<<<nb_e, 256, 0, stream>>>(col, cnt, E);
        kS1<<<nb_n, 256, 0, stream>>>(cnt, ptr, bsum, N);
        kS2<<<1, 512, 0, stream>>>(bsum, ptr, nb_n, N);
        kS3<<<nb_n, 256, 0, stream>>>(ptr, cnt, bsum, N);
        k_fill<<<nb_e, 256, 0, stream>>>(row, col, ew, cnt, packed, E);
        k_degw<<<nb_w, 256, 0, stream>>>(packed, ptr, dinv, N);
        if (ws_size >= need_full)
            k_gatherb<<<nb_w, 256, 0, stream>>>(packed, ptr, dinv, tab, out, N);
        else
            k_gather<<<nb_w, 256, 0, stream>>>(packed, ptr, dinv, nf, out, N);
    } else {
        float* deg = (float*)d_ws;
        sums = (float*)d_ws + N;
        k_initA<<<nb_n, 256, 0, stream>>>(deg, sums, N);
        k_deg<<<nb_e, 256, 0, stream>>>(col, ew, deg, E);
        k_dinv<<<nb_n, 256, 0, stream>>>(deg, N);
        k_self<<<nb_v4, 256, 0, stream>>>(nf, deg, out, N);
        k_scatter<<<(E + 3) / 4, 256, 0, stream>>>(row, col, ew, deg, nf, out, E);
    }
    k_gemm2<<<(N + 127) / 128, 256, 0, stream>>>(out, W, bias, sums, N);
    k_bnfin<<<1, 128, 0, stream>>>(sums, gamma, beta, N);
    k_bnapply<<<nb_v4, 256, 0, stream>>>(out, sums, (size_t)N * 32);
}